// Round 5
// baseline (2867.177 us; speedup 1.0000x reference)
//
#include <hip/hip_runtime.h>
#include <cstdint>

#define HN 64
#define HE 64
#define NNODE 50000
#define NEDGE 200000
#define NTRIP 600000
#define EPSBN 1e-5f

// ws layout (u32 units):
//   [0:768)        gstats (floats)
//   [768:1536)     scales (floats)
//   [1536:22016)   w3f_hi  (10 stages * 8 ni * 64 lanes * 4 u32)
//   [22016:42496)  w3f_lo
//   [42496: +12.8M) agg (E*64 floats)
//   then (fast path only) c3h: T*128 bf16 = 38.4M u32   -> total ~205 MB
// gstats: c2_sum(128) c2_sq(128) c3_sum(128) c3_sq(128) u_sum(64) u_sq(64) agg_sum(64) agg_sq(64)
// scales: c2_scale(128) c2_shift(128) c3_scale(128) c3_shift(128) u_s(64) u_h(64) agg_s(64) agg_h(64)

typedef __attribute__((ext_vector_type(8))) short short8;
typedef __attribute__((ext_vector_type(4))) float f32x4;

__device__ __forceinline__ float sigmoid_f(float x) {
    return 1.0f / (1.0f + __expf(-x));
}
__device__ __forceinline__ float tanh_f(float x) {
    return 1.0f - 2.0f / (__expf(2.0f * x) + 1.0f);
}
__device__ __forceinline__ short8 as_s8(uint4 v) {
    union { uint4 u; short8 s; } c; c.u = v; return c.s;
}
__device__ __forceinline__ unsigned short bf16_rne(float v) {
    const unsigned b = __float_as_uint(v);
    return (unsigned short)((b + 0x7FFFu + ((b >> 16) & 1u)) >> 16);
}

// convert 16 fp32 -> 8 packed bf16-hi u32 (and optionally lo), 2x b128 LDS writes
__device__ __forceinline__ void cvt_store16(
    const float4* x, unsigned int* __restrict__ dhi,
    unsigned int* __restrict__ dlo, bool do_lo)
{
    float xv[16] = {x[0].x, x[0].y, x[0].z, x[0].w, x[1].x, x[1].y, x[1].z, x[1].w,
                    x[2].x, x[2].y, x[2].z, x[2].w, x[3].x, x[3].y, x[3].z, x[3].w};
    unsigned hu[16];
#pragma unroll
    for (int e = 0; e < 16; ++e) hu[e] = __float_as_uint(xv[e]) >> 16;  // truncate split
    uint4 ph0, ph1;
    ph0.x = (hu[1] << 16) | hu[0];  ph0.y = (hu[3] << 16) | hu[2];
    ph0.z = (hu[5] << 16) | hu[4];  ph0.w = (hu[7] << 16) | hu[6];
    ph1.x = (hu[9] << 16) | hu[8];  ph1.y = (hu[11] << 16) | hu[10];
    ph1.z = (hu[13] << 16) | hu[12]; ph1.w = (hu[15] << 16) | hu[14];
    *reinterpret_cast<uint4*>(dhi) = ph0;
    *reinterpret_cast<uint4*>(dhi + 4) = ph1;
    if (do_lo) {
        unsigned lu[16];
#pragma unroll
        for (int e = 0; e < 16; ++e) {
            const float hf = __uint_as_float(hu[e] << 16);
            lu[e] = __float_as_uint(xv[e] - hf) >> 16;  // exact residual, trunc to bf16
        }
        uint4 pl0, pl1;
        pl0.x = (lu[1] << 16) | lu[0];  pl0.y = (lu[3] << 16) | lu[2];
        pl0.z = (lu[5] << 16) | lu[4];  pl0.w = (lu[7] << 16) | lu[6];
        pl1.x = (lu[9] << 16) | lu[8];  pl1.y = (lu[11] << 16) | lu[10];
        pl1.z = (lu[13] << 16) | lu[12]; pl1.w = (lu[15] << 16) | lu[14];
        *reinterpret_cast<uint4*>(dlo) = pl0;
        *reinterpret_cast<uint4*>(dlo + 4) = pl1;
    }
}

// ---------------------------------------------------------------------------
// pack W3 into MFMA B-fragment layout, bf16 hi/lo planes.
// element o = ((s*8 + ni)*64 + lane)*4 + m  holds W3[n][k],W3[n][k+1] packed,
// n = ni*16 + (lane&15), k = s*32 + (lane>>4)*8 + 2m.
// ---------------------------------------------------------------------------
__global__ void k_pack_w3(const float* __restrict__ W3,
                          unsigned* __restrict__ w3f_hi, unsigned* __restrict__ w3f_lo)
{
    const int o = blockIdx.x * 256 + threadIdx.x;
    if (o >= 10 * 8 * 64 * 4) return;
    const int m = o & 3, lane = (o >> 2) & 63, ni = (o >> 8) & 7, s = o >> 11;
    const int n = ni * 16 + (lane & 15);
    const int k = s * 32 + (lane >> 4) * 8 + 2 * m;
    const float a = W3[(size_t)n * 320 + k], b = W3[(size_t)n * 320 + k + 1];
    const unsigned ah = __float_as_uint(a) >> 16, bh = __float_as_uint(b) >> 16;
    w3f_hi[o] = (bh << 16) | ah;
    const float ar = a - __uint_as_float(ah << 16);
    const float br = b - __uint_as_float(bh << 16);
    w3f_lo[o] = ((__float_as_uint(br) >> 16) << 16) | (__float_as_uint(ar) >> 16);
}

// ---------------------------------------------------------------------------
// c3 GEMM via bf16 MFMA. A gathered fp32->hi/lo in LDS (prefetch depth 2);
// B fragments straight from w3f planes in global (L2-hot, no LDS, no cvt).
// MODE 0: 1-term, stats only (slow-path pass 1)
// MODE 1: 3-term, stats + store C as bf16 to c3h (fast-path single GEMM)
// MODE 2: 3-term, BN + gate + scatter to agg (slow-path pass 2)
// ---------------------------------------------------------------------------
template <int MODE>
__global__ __launch_bounds__(256) void k_gemm_c3_mfma(
    const float* __restrict__ node, const float* __restrict__ edge,
    const int* __restrict__ idx_i, const int* __restrict__ idx_j,
    const int* __restrict__ idx_k, const int* __restrict__ idx_ji,
    const int* __restrict__ idx_kj,
    const unsigned* __restrict__ w3f_hi, const unsigned* __restrict__ w3f_lo,
    float* __restrict__ gsum, float* __restrict__ gsq,
    const float* __restrict__ scales, float* __restrict__ agg,
    unsigned short* __restrict__ c3h)
{
    constexpr int TERMS = (MODE == 0) ? 1 : 3;
    constexpr int LDA = 20;                    // u32 stride per row (16B-aligned)
    constexpr int PLANE = 128 * LDA;

    __shared__ unsigned int sA[PLANE * ((TERMS == 1) ? 1 : 2)];
    __shared__ float sstat[256];

    const int tid = threadIdx.x;
    const int lane = tid & 63;
    const int w = tid >> 6;
    const int quad = lane >> 4;
    const int l16 = lane & 15;
    const int bm = blockIdx.x * 128;

    const int srow = tid >> 1;
    const int shalf = tid & 1;
    int g = bm + srow;
    if (g >= NTRIP) g = NTRIP - 1;
    const int r0 = idx_i[g], r1 = idx_j[g], r2 = idx_k[g];
    const int r3 = idx_ji[g], r4 = idx_kj[g];

    const float* const srcs0 = node + (size_t)r0 * 64;
    const float* const srcs1 = node + (size_t)r1 * 64;
    const float* const srcs2 = node + (size_t)r2 * 64;
    const float* const srcs3 = edge + (size_t)r3 * 64;
    const float* const srcs4 = edge + (size_t)r4 * 64;

    f32x4 acc[2][8];
#pragma unroll
    for (int mi = 0; mi < 2; ++mi)
#pragma unroll
        for (int ni = 0; ni < 8; ++ni) acc[mi][ni] = (f32x4){0.f, 0.f, 0.f, 0.f};

    float4 bufA[2][4];

#define LOAD_A(S, DST)                                                          \
    do {                                                                        \
        const int seg_ = (S) >> 1;                                              \
        const float* p_;                                                        \
        switch (seg_) {                                                         \
            case 0: p_ = srcs0; break;                                          \
            case 1: p_ = srcs1; break;                                          \
            case 2: p_ = srcs2; break;                                          \
            case 3: p_ = srcs3; break;                                          \
            default: p_ = srcs4; break;                                         \
        }                                                                       \
        const float4* q_ = reinterpret_cast<const float4*>(                     \
            p_ + ((S) & 1) * 32 + shalf * 16);                                  \
        (DST)[0] = q_[0]; (DST)[1] = q_[1]; (DST)[2] = q_[2]; (DST)[3] = q_[3]; \
    } while (0)

    LOAD_A(0, bufA[0]);
    LOAD_A(1, bufA[1]);

    unsigned int* const dA = sA + srow * LDA + shalf * 8;
    const uint4* const wph = reinterpret_cast<const uint4*>(w3f_hi) + lane;
    const uint4* const wpl = reinterpret_cast<const uint4*>(w3f_lo) + lane;

#pragma unroll
    for (int s = 0; s < 10; ++s) {
        __syncthreads();  // prior stage's fragment reads done
        cvt_store16(bufA[s & 1], dA, dA + PLANE, TERMS == 3);
        if (s + 2 < 10) LOAD_A(s + 2, bufA[s & 1]);
        __syncthreads();

        // B fragments for this stage: direct global loads (L2-broadcast)
        uint4 bhi[8], blo[8];
#pragma unroll
        for (int ni = 0; ni < 8; ++ni) bhi[ni] = wph[(s * 8 + ni) * 64];
        if (TERMS == 3) {
#pragma unroll
            for (int ni = 0; ni < 8; ++ni) blo[ni] = wpl[(s * 8 + ni) * 64];
        }

        uint4 ahi[2], alo[2];
#pragma unroll
        for (int mi = 0; mi < 2; ++mi) {
            const int abase = (w * 32 + mi * 16 + l16) * LDA + quad * 4;
            ahi[mi] = *reinterpret_cast<const uint4*>(&sA[abase]);
            if (TERMS == 3) alo[mi] = *reinterpret_cast<const uint4*>(&sA[PLANE + abase]);
        }
#pragma unroll
        for (int ni = 0; ni < 8; ++ni) {
#pragma unroll
            for (int mi = 0; mi < 2; ++mi)
                acc[mi][ni] = __builtin_amdgcn_mfma_f32_16x16x32_bf16(
                    as_s8(ahi[mi]), as_s8(bhi[ni]), acc[mi][ni], 0, 0, 0);
            if (TERMS == 3) {
#pragma unroll
                for (int mi = 0; mi < 2; ++mi) {
                    acc[mi][ni] = __builtin_amdgcn_mfma_f32_16x16x32_bf16(
                        as_s8(ahi[mi]), as_s8(blo[ni]), acc[mi][ni], 0, 0, 0);
                    acc[mi][ni] = __builtin_amdgcn_mfma_f32_16x16x32_bf16(
                        as_s8(alo[mi]), as_s8(bhi[ni]), acc[mi][ni], 0, 0, 0);
                }
            }
        }
    }
#undef LOAD_A

    // C/D layout: col = ni*16 + l16, row = w*32 + mi*16 + quad*4 + reg
    if (MODE == 1) {
#pragma unroll
        for (int mi = 0; mi < 2; ++mi)
#pragma unroll
            for (int reg = 0; reg < 4; ++reg) {
                const int grow = bm + w * 32 + mi * 16 + quad * 4 + reg;
                if (grow < NTRIP) {
                    unsigned short* dst = c3h + (size_t)grow * 128 + l16;
#pragma unroll
                    for (int ni = 0; ni < 8; ++ni)
                        dst[ni * 16] = bf16_rne(acc[mi][ni][reg]);
                }
            }
    }

    if (MODE == 0 || MODE == 1) {
        __syncthreads();
        sstat[tid] = 0.0f;
        __syncthreads();
#pragma unroll
        for (int ni = 0; ni < 8; ++ni) {
            const int col = ni * 16 + l16;
            float s = 0.0f, q = 0.0f;
#pragma unroll
            for (int mi = 0; mi < 2; ++mi)
#pragma unroll
                for (int reg = 0; reg < 4; ++reg) {
                    const int grow = bm + w * 32 + mi * 16 + quad * 4 + reg;
                    if (grow < NTRIP) {
                        const float v = acc[mi][ni][reg];
                        s += v; q += v * v;
                    }
                }
            atomicAdd(&sstat[col], s);
            atomicAdd(&sstat[128 + col], q);
        }
        __syncthreads();
        if (tid < 128) {
            atomicAdd(&gsum[tid], sstat[tid]);
            atomicAdd(&gsq[tid], sstat[128 + tid]);
        }
    }

    if (MODE == 2) {
        float sf[4], hf[4], sc[4], hc[4];
#pragma unroll
        for (int ni = 0; ni < 4; ++ni) {
            const int col = ni * 16 + l16;
            sf[ni] = scales[256 + col];      hf[ni] = scales[384 + col];
            sc[ni] = scales[256 + 64 + col]; hc[ni] = scales[384 + 64 + col];
        }
#pragma unroll
        for (int mi = 0; mi < 2; ++mi)
#pragma unroll
            for (int reg = 0; reg < 4; ++reg) {
                const int grow = bm + w * 32 + mi * 16 + quad * 4 + reg;
                if (grow < NTRIP) {
                    const int e = idx_ji[grow];
                    float* dst = &agg[(size_t)e * 64 + l16];
#pragma unroll
                    for (int ni = 0; ni < 4; ++ni) {
                        const float fv = acc[mi][ni][reg] * sf[ni] + hf[ni];
                        const float cv = acc[mi][ni + 4][reg] * sc[ni] + hc[ni];
                        atomicAdd(dst + ni * 16, sigmoid_f(fv) * tanh_f(cv));
                    }
                }
            }
    }
}

// ---------------------------------------------------------------------------
// fast-path pass 2: read bf16 c3, BN + gate + scatter. 4 threads per row.
// ---------------------------------------------------------------------------
__global__ __launch_bounds__(256) void k_apply3(
    const unsigned short* __restrict__ c3h, const float* __restrict__ scales,
    const int* __restrict__ idx_ji, float* __restrict__ agg)
{
    __shared__ float s_sf[64], s_hf[64], s_sc[64], s_hc[64];
    const int tid = threadIdx.x;
    if (tid < 64) {
        s_sf[tid] = scales[256 + tid]; s_hf[tid] = scales[384 + tid];
        s_sc[tid] = scales[320 + tid]; s_hc[tid] = scales[448 + tid];
    }
    __syncthreads();
    const int idx = blockIdx.x * 256 + tid;   // grid sized exactly: T*4 threads
    const int row = idx >> 2;
    const int h = idx & 3;
    const uint4* pf = reinterpret_cast<const uint4*>(&c3h[(size_t)row * 128 + h * 16]);
    const uint4 f0 = pf[0], f1 = pf[1];
    const uint4* pc = reinterpret_cast<const uint4*>(&c3h[(size_t)row * 128 + 64 + h * 16]);
    const uint4 c0 = pc[0], c1 = pc[1];
    const int e = idx_ji[row];
    float* dst = &agg[(size_t)e * 64 + h * 16];
    const unsigned fw[8] = {f0.x, f0.y, f0.z, f0.w, f1.x, f1.y, f1.z, f1.w};
    const unsigned cw[8] = {c0.x, c0.y, c0.z, c0.w, c1.x, c1.y, c1.z, c1.w};
#pragma unroll
    for (int p = 0; p < 8; ++p) {
        const int col0 = h * 16 + 2 * p;
        const float fa = __uint_as_float(fw[p] << 16);
        const float fb = __uint_as_float(fw[p] & 0xFFFF0000u);
        const float ca = __uint_as_float(cw[p] << 16);
        const float cb = __uint_as_float(cw[p] & 0xFFFF0000u);
        const float m0 = sigmoid_f(fa * s_sf[col0] + s_hf[col0]) *
                         tanh_f(ca * s_sc[col0] + s_hc[col0]);
        const float m1 = sigmoid_f(fb * s_sf[col0 + 1] + s_hf[col0 + 1]) *
                         tanh_f(cb * s_sc[col0 + 1] + s_hc[col0 + 1]);
        atomicAdd(dst + 2 * p, m0);
        atomicAdd(dst + 2 * p + 1, m1);
    }
}

// ---------------------------------------------------------------------------
// c2 GEMM (K=64, VALU) — unchanged
// ---------------------------------------------------------------------------
template <int MODE>
__global__ __launch_bounds__(256) void k_gemm_c2(
    const float* __restrict__ node, const int* __restrict__ vi,
    const int* __restrict__ vj, const float* __restrict__ W2,
    float* __restrict__ gsum, float* __restrict__ gsq,
    const float* __restrict__ scales, float* __restrict__ uout,
    float* __restrict__ usum, float* __restrict__ usq)
{
    __shared__ float sA[32][132];
    __shared__ float sB[32][132];
    __shared__ float sstat[256];

    const int tid = threadIdx.x;
    const int tx = tid & 15, ty = tid >> 4;
    const int bm = blockIdx.x * 128;

    float acc[8][8];
#pragma unroll
    for (int i = 0; i < 8; ++i)
#pragma unroll
        for (int j = 0; j < 8; ++j) acc[i][j] = 0.0f;

    const int mstage = tid >> 1;
    const int kq = (tid & 1) * 16;
    int g = bm + mstage;
    if (g >= NEDGE) g = NEDGE - 1;
    const int r0 = vi[g], r1 = vj[g];

    for (int s = 0; s < 2; ++s) {
        const int kin = s * 32;
        const float4* pa = reinterpret_cast<const float4*>(node + (size_t)r0 * 64 + kin + kq);
        const float4* pc = reinterpret_cast<const float4*>(node + (size_t)r1 * 64 + kin + kq);
        float4 v0 = pa[0], v1 = pa[1], v2 = pa[2], v3 = pa[3];
        float4 u0 = pc[0], u1 = pc[1], u2 = pc[2], u3 = pc[3];
        const float4* pb = reinterpret_cast<const float4*>(W2 + (size_t)mstage * 64 + kin + kq);
        float4 w0 = pb[0], w1 = pb[1], w2 = pb[2], w3 = pb[3];

        __syncthreads();
        const float va[16] = {v0.x*u0.x, v0.y*u0.y, v0.z*u0.z, v0.w*u0.w,
                              v1.x*u1.x, v1.y*u1.y, v1.z*u1.z, v1.w*u1.w,
                              v2.x*u2.x, v2.y*u2.y, v2.z*u2.z, v2.w*u2.w,
                              v3.x*u3.x, v3.y*u3.y, v3.z*u3.z, v3.w*u3.w};
        const float vb[16] = {w0.x,w0.y,w0.z,w0.w, w1.x,w1.y,w1.z,w1.w,
                              w2.x,w2.y,w2.z,w2.w, w3.x,w3.y,w3.z,w3.w};
#pragma unroll
        for (int u = 0; u < 16; ++u) sA[kq + u][mstage] = va[u];
#pragma unroll
        for (int u = 0; u < 16; ++u) sB[kq + u][mstage] = vb[u];
        __syncthreads();

#pragma unroll 4
        for (int k = 0; k < 32; ++k) {
            const float4 a0 = *reinterpret_cast<const float4*>(&sA[k][ty * 4]);
            const float4 a1 = *reinterpret_cast<const float4*>(&sA[k][64 + ty * 4]);
            const float4 b0 = *reinterpret_cast<const float4*>(&sB[k][tx * 4]);
            const float4 b1 = *reinterpret_cast<const float4*>(&sB[k][64 + tx * 4]);
            const float av[8] = {a0.x,a0.y,a0.z,a0.w, a1.x,a1.y,a1.z,a1.w};
            const float bv[8] = {b0.x,b0.y,b0.z,b0.w, b1.x,b1.y,b1.z,b1.w};
#pragma unroll
            for (int i = 0; i < 8; ++i)
#pragma unroll
                for (int j = 0; j < 8; ++j)
                    acc[i][j] = fmaf(av[i], bv[j], acc[i][j]);
        }
    }

    int rowg[8];
#pragma unroll
    for (int i = 0; i < 8; ++i) {
        const int m = (i < 4) ? (ty * 4 + i) : (64 + ty * 4 + (i - 4));
        rowg[i] = bm + m;
    }

    if (MODE == 0) {
        __syncthreads();
        sstat[tid] = 0.0f;
        __syncthreads();
#pragma unroll
        for (int j = 0; j < 8; ++j) {
            const int n = (j < 4) ? (tx * 4 + j) : (64 + tx * 4 + (j - 4));
            float s = 0.0f, q = 0.0f;
#pragma unroll
            for (int i = 0; i < 8; ++i) {
                if (rowg[i] < NEDGE) { s += acc[i][j]; q += acc[i][j] * acc[i][j]; }
            }
            atomicAdd(&sstat[n], s);
            atomicAdd(&sstat[128 + n], q);
        }
        __syncthreads();
        if (tid < 128) {
            atomicAdd(&gsum[tid], sstat[tid]);
            atomicAdd(&gsq[tid], sstat[128 + tid]);
        }
    }

    if (MODE == 2) {
        float sf[4], hf[4], sc[4], hc[4];
#pragma unroll
        for (int j = 0; j < 4; ++j) {
            const int col = tx * 4 + j;
            sf[j] = scales[col];      hf[j] = scales[128 + col];
            sc[j] = scales[64 + col]; hc[j] = scales[128 + 64 + col];
        }
        __syncthreads();
        sstat[tid] = 0.0f;
        __syncthreads();
        float lsum[4] = {0, 0, 0, 0}, lsq[4] = {0, 0, 0, 0};
#pragma unroll
        for (int i = 0; i < 8; ++i) {
            if (rowg[i] < NEDGE) {
                float uv[4];
#pragma unroll
                for (int j = 0; j < 4; ++j) {
                    const float f = acc[i][j] * sf[j] + hf[j];
                    const float c = acc[i][j + 4] * sc[j] + hc[j];
                    uv[j] = sigmoid_f(f) * tanh_f(c);
                    lsum[j] += uv[j]; lsq[j] += uv[j] * uv[j];
                }
                *reinterpret_cast<float4*>(&uout[(size_t)rowg[i] * 64 + tx * 4]) =
                    make_float4(uv[0], uv[1], uv[2], uv[3]);
            }
        }
#pragma unroll
        for (int j = 0; j < 4; ++j) {
            atomicAdd(&sstat[tx * 4 + j], lsum[j]);
            atomicAdd(&sstat[128 + tx * 4 + j], lsq[j]);
        }
        __syncthreads();
        if (tid < 64) {
            atomicAdd(&usum[tid], sstat[tid]);
            atomicAdd(&usq[tid], sstat[128 + tid]);
        }
    }
}

// ---------------------------------------------------------------------------
__global__ void k_finalize1(const float* __restrict__ gstats,
                            const float* __restrict__ g_c2, const float* __restrict__ beta_c2,
                            const float* __restrict__ g_c3, const float* __restrict__ beta_c3,
                            float* __restrict__ scales)
{
    const int t = threadIdx.x;
    if (t < 128) {
        const float inv = 1.0f / (float)NEDGE;
        const float mean = gstats[t] * inv;
        const float var = gstats[128 + t] * inv - mean * mean;
        const float sc = g_c2[t] * rsqrtf(var + EPSBN);
        scales[t] = sc;
        scales[128 + t] = beta_c2[t] - mean * sc;
    } else {
        const int c = t - 128;
        const float inv = 1.0f / (float)NTRIP;
        const float mean = gstats[256 + c] * inv;
        const float var = gstats[384 + c] * inv - mean * mean;
        const float sc = g_c3[c] * rsqrtf(var + EPSBN);
        scales[256 + c] = sc;
        scales[384 + c] = beta_c3[c] - mean * sc;
    }
}

__global__ void k_finalize2(const float* __restrict__ gstats,
                            const float* __restrict__ g_c22, const float* __restrict__ beta_c22,
                            const float* __restrict__ g_c32, const float* __restrict__ beta_c32,
                            float* __restrict__ scales)
{
    const int t = threadIdx.x;
    const float inv = 1.0f / (float)NEDGE;
    if (t < 64) {
        const float mean = gstats[512 + t] * inv;
        const float var = gstats[576 + t] * inv - mean * mean;
        const float sc = g_c22[t] * rsqrtf(var + EPSBN);
        scales[512 + t] = sc;
        scales[576 + t] = beta_c22[t] - mean * sc;
    } else {
        const int c = t - 64;
        const float mean = gstats[640 + c] * inv;
        const float var = gstats[704 + c] * inv - mean * mean;
        const float sc = g_c32[c] * rsqrtf(var + EPSBN);
        scales[640 + c] = sc;
        scales[704 + c] = beta_c32[c] - mean * sc;
    }
}

// ---------------------------------------------------------------------------
__global__ __launch_bounds__(256) void k_stats_agg(
    const float* __restrict__ agg, float* __restrict__ gstats)
{
    const int tid = threadIdx.x;
    const int c4 = tid & 15;
    float ls[4] = {0, 0, 0, 0}, lq[4] = {0, 0, 0, 0};
    const long total = (long)NEDGE * 16;
    const long stride = (long)gridDim.x * blockDim.x;
    for (long idx = (long)blockIdx.x * blockDim.x + tid; idx < total; idx += stride) {
        const int row = (int)(idx >> 4);
        const float4 a = *reinterpret_cast<const float4*>(&agg[(size_t)row * 64 + c4 * 4]);
        ls[0] += a.x; lq[0] += a.x * a.x;
        ls[1] += a.y; lq[1] += a.y * a.y;
        ls[2] += a.z; lq[2] += a.z * a.z;
        ls[3] += a.w; lq[3] += a.w * a.w;
    }
    __shared__ float red[2][16][68];
    const int gr = tid >> 4;
#pragma unroll
    for (int cc = 0; cc < 4; ++cc) {
        red[0][gr][c4 * 4 + cc] = ls[cc];
        red[1][gr][c4 * 4 + cc] = lq[cc];
    }
    __syncthreads();
    if (tid < 64) {
        float s = 0.0f, q = 0.0f;
        for (int g2 = 0; g2 < 16; ++g2) { s += red[0][g2][tid]; q += red[1][g2][tid]; }
        atomicAdd(&gstats[640 + tid], s);
        atomicAdd(&gstats[704 + tid], q);
    }
}

// ---------------------------------------------------------------------------
__global__ __launch_bounds__(256) void k_final(
    const float* __restrict__ edge, const float* __restrict__ agg,
    const float* __restrict__ scales, float* __restrict__ out)
{
    const int tid = threadIdx.x;
    const int c4 = tid & 15;
    float su[4], hu[4], sa[4], ha[4];
#pragma unroll
    for (int cc = 0; cc < 4; ++cc) {
        const int col = c4 * 4 + cc;
        su[cc] = scales[512 + col]; hu[cc] = scales[576 + col];
        sa[cc] = scales[640 + col]; ha[cc] = scales[704 + col];
    }
    const long total = (long)NEDGE * 16;
    const long stride = (long)gridDim.x * blockDim.x;
    for (long idx = (long)blockIdx.x * blockDim.x + tid; idx < total; idx += stride) {
        const int row = (int)(idx >> 4);
        const size_t base = (size_t)row * 64 + c4 * 4;
        const float4 e = *reinterpret_cast<const float4*>(&edge[base]);
        const float4 u = *reinterpret_cast<const float4*>(&out[base]);
        const float4 a = *reinterpret_cast<const float4*>(&agg[base]);
        float4 o;
        o.x = tanh_f(e.x + u.x * su[0] + hu[0] + a.x * sa[0] + ha[0]);
        o.y = tanh_f(e.y + u.y * su[1] + hu[1] + a.y * sa[1] + ha[1]);
        o.z = tanh_f(e.z + u.z * su[2] + hu[2] + a.z * sa[2] + ha[2]);
        o.w = tanh_f(e.w + u.w * su[3] + hu[3] + a.w * sa[3] + ha[3]);
        *reinterpret_cast<float4*>(&out[base]) = o;
    }
}

// ---------------------------------------------------------------------------
extern "C" void kernel_launch(void* const* d_in, const int* in_sizes, int n_in,
                              void* d_out, int out_size, void* d_ws, size_t ws_size,
                              hipStream_t stream)
{
    (void)in_sizes; (void)n_in; (void)out_size;
    const float* node   = (const float*)d_in[0];
    const float* edge   = (const float*)d_in[1];
    const int*   vi     = (const int*)d_in[2];
    const int*   vj     = (const int*)d_in[3];
    const int*   idx_i  = (const int*)d_in[4];
    const int*   idx_j  = (const int*)d_in[5];
    const int*   idx_k  = (const int*)d_in[6];
    const int*   idx_ji = (const int*)d_in[7];
    const int*   idx_kj = (const int*)d_in[8];
    const float* W2     = (const float*)d_in[9];
    // d_in[10] = b2: cancels inside BN (mean subtraction)
    const float* W3     = (const float*)d_in[11];
    // d_in[12] = b3: cancels inside BN
    const float* g_c2    = (const float*)d_in[13];
    const float* beta_c2 = (const float*)d_in[14];
    const float* g_c3    = (const float*)d_in[15];
    const float* beta_c3 = (const float*)d_in[16];
    const float* g_c22    = (const float*)d_in[17];
    const float* beta_c22 = (const float*)d_in[18];
    const float* g_c32    = (const float*)d_in[19];
    const float* beta_c32 = (const float*)d_in[20];
    float* out = (float*)d_out;

    unsigned* wsu   = (unsigned*)d_ws;
    float* gstats   = (float*)wsu;                    // u32 [0:768)
    float* scales   = (float*)(wsu + 768);            // [768:1536)
    unsigned* w3f_hi = wsu + 1536;                    // [1536:22016)
    unsigned* w3f_lo = wsu + 22016;                   // [22016:42496)
    float* agg      = (float*)(wsu + 42496);          // E*64 floats
    unsigned short* c3h = (unsigned short*)(wsu + 42496 + (size_t)NEDGE * 64);

    const size_t need_fast =
        (42496 + (size_t)NEDGE * 64 + (size_t)NTRIP * 64) * 4;  // ~205 MB
    const bool fast = (ws_size >= need_fast);

    hipMemsetAsync(gstats, 0, 768 * sizeof(float), stream);
    hipMemsetAsync(agg, 0, (size_t)NEDGE * 64 * sizeof(float), stream);

    const int grid_c2 = (NEDGE + 127) / 128;
    const int grid_c3 = (NTRIP + 127) / 128;

    k_pack_w3<<<80, 256, 0, stream>>>(W3, w3f_hi, w3f_lo);

    // pass 1: column stats (fast: 3-term + bf16 store of c3; slow: 1-term)
    k_gemm_c2<0><<<grid_c2, 256, 0, stream>>>(
        node, vi, vj, W2, gstats + 0, gstats + 128, nullptr, nullptr, nullptr, nullptr);
    if (fast) {
        k_gemm_c3_mfma<1><<<grid_c3, 256, 0, stream>>>(
            node, edge, idx_i, idx_j, idx_k, idx_ji, idx_kj, w3f_hi, w3f_lo,
            gstats + 256, gstats + 384, nullptr, nullptr, c3h);
    } else {
        k_gemm_c3_mfma<0><<<grid_c3, 256, 0, stream>>>(
            node, edge, idx_i, idx_j, idx_k, idx_ji, idx_kj, w3f_hi, w3f_lo,
            gstats + 256, gstats + 384, nullptr, nullptr, nullptr);
    }
    k_finalize1<<<1, 256, 0, stream>>>(gstats, g_c2, beta_c2, g_c3, beta_c3, scales);

    // pass 2: apply BN + gates; u -> d_out (scratch), msg -> agg (atomics)
    k_gemm_c2<2><<<grid_c2, 256, 0, stream>>>(
        node, vi, vj, W2, nullptr, nullptr, scales, out, gstats + 512, gstats + 576);
    if (fast) {
        k_apply3<<<(NTRIP * 4) / 256, 256, 0, stream>>>(c3h, scales, idx_ji, agg);
    } else {
        k_gemm_c3_mfma<2><<<grid_c3, 256, 0, stream>>>(
            node, edge, idx_i, idx_j, idx_k, idx_ji, idx_kj, w3f_hi, w3f_lo,
            nullptr, nullptr, scales, agg, nullptr);
    }

    k_stats_agg<<<3072, 256, 0, stream>>>(agg, gstats);
    k_finalize2<<<1, 128, 0, stream>>>(gstats, g_c22, beta_c22, g_c32, beta_c32, scales);
    k_final<<<3072, 256, 0, stream>>>(edge, agg, scales, out);
}

// Round 6
// 888.814 us; speedup vs baseline: 3.2258x; 3.2258x over previous
//
#include <hip/hip_runtime.h>
#include <cstdint>

#define HN 64
#define HE 64
#define NNODE 50000
#define NEDGE 200000
#define NTRIP 600000
#define EPSBN 1e-5f

// ws layout (u32 units):
//   [0:768)        gstats (floats)
//   [768:1536)     scales (floats)
//   [1536:22016)   w3f_hi  (10 stages * 8 ni * 64 lanes * 4 u32)
//   [22016:42496)  w3f_lo
//   [42496: +12.8M) agg (E*64 floats)
//   then (fast path only) c3h: T*128 bf16 = 38.4M u32   -> total ~205 MB
// gstats: c2_sum(128) c2_sq(128) c3_sum(128) c3_sq(128) u_sum(64) u_sq(64) agg_sum(64) agg_sq(64)
// scales: c2_scale(128) c2_shift(128) c3_scale(128) c3_shift(128) u_s(64) u_h(64) agg_s(64) agg_h(64)

typedef __attribute__((ext_vector_type(8))) short short8;
typedef __attribute__((ext_vector_type(4))) float f32x4;

__device__ __forceinline__ float sigmoid_f(float x) {
    return 1.0f / (1.0f + __expf(-x));
}
__device__ __forceinline__ float tanh_f(float x) {
    return 1.0f - 2.0f / (__expf(2.0f * x) + 1.0f);
}
__device__ __forceinline__ short8 as_s8(uint4 v) {
    union { uint4 u; short8 s; } c; c.u = v; return c.s;
}
__device__ __forceinline__ unsigned short bf16_rne(float v) {
    const unsigned b = __float_as_uint(v);
    return (unsigned short)((b + 0x7FFFu + ((b >> 16) & 1u)) >> 16);
}

// convert 16 fp32 -> 8 packed bf16-hi u32 (and optionally lo), 2x b128 LDS writes
__device__ __forceinline__ void cvt_store16(
    const float4* x, unsigned int* __restrict__ dhi,
    unsigned int* __restrict__ dlo, bool do_lo)
{
    float xv[16] = {x[0].x, x[0].y, x[0].z, x[0].w, x[1].x, x[1].y, x[1].z, x[1].w,
                    x[2].x, x[2].y, x[2].z, x[2].w, x[3].x, x[3].y, x[3].z, x[3].w};
    unsigned hu[16];
#pragma unroll
    for (int e = 0; e < 16; ++e) hu[e] = __float_as_uint(xv[e]) >> 16;  // truncate split
    uint4 ph0, ph1;
    ph0.x = (hu[1] << 16) | hu[0];  ph0.y = (hu[3] << 16) | hu[2];
    ph0.z = (hu[5] << 16) | hu[4];  ph0.w = (hu[7] << 16) | hu[6];
    ph1.x = (hu[9] << 16) | hu[8];  ph1.y = (hu[11] << 16) | hu[10];
    ph1.z = (hu[13] << 16) | hu[12]; ph1.w = (hu[15] << 16) | hu[14];
    *reinterpret_cast<uint4*>(dhi) = ph0;
    *reinterpret_cast<uint4*>(dhi + 4) = ph1;
    if (do_lo) {
        unsigned lu[16];
#pragma unroll
        for (int e = 0; e < 16; ++e) {
            const float hf = __uint_as_float(hu[e] << 16);
            lu[e] = __float_as_uint(xv[e] - hf) >> 16;  // exact residual, trunc to bf16
        }
        uint4 pl0, pl1;
        pl0.x = (lu[1] << 16) | lu[0];  pl0.y = (lu[3] << 16) | lu[2];
        pl0.z = (lu[5] << 16) | lu[4];  pl0.w = (lu[7] << 16) | lu[6];
        pl1.x = (lu[9] << 16) | lu[8];  pl1.y = (lu[11] << 16) | lu[10];
        pl1.z = (lu[13] << 16) | lu[12]; pl1.w = (lu[15] << 16) | lu[14];
        *reinterpret_cast<uint4*>(dlo) = pl0;
        *reinterpret_cast<uint4*>(dlo + 4) = pl1;
    }
}

// ---------------------------------------------------------------------------
// pack W3 into MFMA B-fragment layout, bf16 hi/lo planes.
// ---------------------------------------------------------------------------
__global__ void k_pack_w3(const float* __restrict__ W3,
                          unsigned* __restrict__ w3f_hi, unsigned* __restrict__ w3f_lo)
{
    const int o = blockIdx.x * 256 + threadIdx.x;
    if (o >= 10 * 8 * 64 * 4) return;
    const int m = o & 3, lane = (o >> 2) & 63, ni = (o >> 8) & 7, s = o >> 11;
    const int n = ni * 16 + (lane & 15);
    const int k = s * 32 + (lane >> 4) * 8 + 2 * m;
    const float a = W3[(size_t)n * 320 + k], b = W3[(size_t)n * 320 + k + 1];
    const unsigned ah = __float_as_uint(a) >> 16, bh = __float_as_uint(b) >> 16;
    w3f_hi[o] = (bh << 16) | ah;
    const float ar = a - __uint_as_float(ah << 16);
    const float br = b - __uint_as_float(bh << 16);
    w3f_lo[o] = ((__float_as_uint(br) >> 16) << 16) | (__float_as_uint(ar) >> 16);
}

// ---------------------------------------------------------------------------
// c3 GEMM via bf16 MFMA. A gathered fp32->hi/lo in LDS (prefetch depth 2);
// B fragments straight from w3f planes in global (L2-hot, no LDS, no cvt).
// MODE 0: 1-term, stats only (slow-path pass 1)
// MODE 1: 3-term, stats + store C as bf16 to c3h (fast-path single GEMM)
// MODE 2: 3-term, BN + gate + scatter to agg (slow-path pass 2)
// ---------------------------------------------------------------------------
template <int MODE>
__global__ __launch_bounds__(256) void k_gemm_c3_mfma(
    const float* __restrict__ node, const float* __restrict__ edge,
    const int* __restrict__ idx_i, const int* __restrict__ idx_j,
    const int* __restrict__ idx_k, const int* __restrict__ idx_ji,
    const int* __restrict__ idx_kj,
    const unsigned* __restrict__ w3f_hi, const unsigned* __restrict__ w3f_lo,
    float* __restrict__ gsum, float* __restrict__ gsq,
    const float* __restrict__ scales, float* __restrict__ agg,
    unsigned short* __restrict__ c3h)
{
    constexpr int TERMS = (MODE == 0) ? 1 : 3;
    constexpr int LDA = 20;                    // u32 stride per row (16B-aligned)
    constexpr int PLANE = 128 * LDA;

    __shared__ unsigned int sA[PLANE * ((TERMS == 1) ? 1 : 2)];
    __shared__ float sstat[256];

    const int tid = threadIdx.x;
    const int lane = tid & 63;
    const int w = tid >> 6;
    const int quad = lane >> 4;
    const int l16 = lane & 15;
    const int bm = blockIdx.x * 128;

    const int srow = tid >> 1;
    const int shalf = tid & 1;
    int g = bm + srow;
    if (g >= NTRIP) g = NTRIP - 1;
    const int r0 = idx_i[g], r1 = idx_j[g], r2 = idx_k[g];
    const int r3 = idx_ji[g], r4 = idx_kj[g];

    const float* const srcs0 = node + (size_t)r0 * 64;
    const float* const srcs1 = node + (size_t)r1 * 64;
    const float* const srcs2 = node + (size_t)r2 * 64;
    const float* const srcs3 = edge + (size_t)r3 * 64;
    const float* const srcs4 = edge + (size_t)r4 * 64;

    f32x4 acc[2][8];
#pragma unroll
    for (int mi = 0; mi < 2; ++mi)
#pragma unroll
        for (int ni = 0; ni < 8; ++ni) acc[mi][ni] = (f32x4){0.f, 0.f, 0.f, 0.f};

    float4 bufA[2][4];

#define LOAD_A(S, DST)                                                          \
    do {                                                                        \
        const int seg_ = (S) >> 1;                                              \
        const float* p_;                                                        \
        switch (seg_) {                                                         \
            case 0: p_ = srcs0; break;                                          \
            case 1: p_ = srcs1; break;                                          \
            case 2: p_ = srcs2; break;                                          \
            case 3: p_ = srcs3; break;                                          \
            default: p_ = srcs4; break;                                         \
        }                                                                       \
        const float4* q_ = reinterpret_cast<const float4*>(                     \
            p_ + ((S) & 1) * 32 + shalf * 16);                                  \
        (DST)[0] = q_[0]; (DST)[1] = q_[1]; (DST)[2] = q_[2]; (DST)[3] = q_[3]; \
    } while (0)

    LOAD_A(0, bufA[0]);
    LOAD_A(1, bufA[1]);

    unsigned int* const dA = sA + srow * LDA + shalf * 8;
    const uint4* const wph = reinterpret_cast<const uint4*>(w3f_hi) + lane;
    const uint4* const wpl = reinterpret_cast<const uint4*>(w3f_lo) + lane;

#pragma unroll
    for (int s = 0; s < 10; ++s) {
        __syncthreads();  // prior stage's fragment reads done
        cvt_store16(bufA[s & 1], dA, dA + PLANE, TERMS == 3);
        if (s + 2 < 10) LOAD_A(s + 2, bufA[s & 1]);
        __syncthreads();

        // B fragments for this stage: direct global loads (L2-broadcast)
        uint4 bhi[8], blo[8];
#pragma unroll
        for (int ni = 0; ni < 8; ++ni) bhi[ni] = wph[(s * 8 + ni) * 64];
        if (TERMS == 3) {
#pragma unroll
            for (int ni = 0; ni < 8; ++ni) blo[ni] = wpl[(s * 8 + ni) * 64];
        }

        uint4 ahi[2], alo[2];
#pragma unroll
        for (int mi = 0; mi < 2; ++mi) {
            const int abase = (w * 32 + mi * 16 + l16) * LDA + quad * 4;
            ahi[mi] = *reinterpret_cast<const uint4*>(&sA[abase]);
            if (TERMS == 3) alo[mi] = *reinterpret_cast<const uint4*>(&sA[PLANE + abase]);
        }
#pragma unroll
        for (int ni = 0; ni < 8; ++ni) {
#pragma unroll
            for (int mi = 0; mi < 2; ++mi)
                acc[mi][ni] = __builtin_amdgcn_mfma_f32_16x16x32_bf16(
                    as_s8(ahi[mi]), as_s8(bhi[ni]), acc[mi][ni], 0, 0, 0);
            if (TERMS == 3) {
#pragma unroll
                for (int mi = 0; mi < 2; ++mi) {
                    acc[mi][ni] = __builtin_amdgcn_mfma_f32_16x16x32_bf16(
                        as_s8(ahi[mi]), as_s8(blo[ni]), acc[mi][ni], 0, 0, 0);
                    acc[mi][ni] = __builtin_amdgcn_mfma_f32_16x16x32_bf16(
                        as_s8(alo[mi]), as_s8(bhi[ni]), acc[mi][ni], 0, 0, 0);
                }
            }
        }
    }
#undef LOAD_A

    // C/D layout: col = ni*16 + l16, row = w*32 + mi*16 + quad*4 + reg
    if (MODE == 1) {
#pragma unroll
        for (int mi = 0; mi < 2; ++mi)
#pragma unroll
            for (int reg = 0; reg < 4; ++reg) {
                const int grow = bm + w * 32 + mi * 16 + quad * 4 + reg;
                if (grow < NTRIP) {
                    unsigned short* dst = c3h + (size_t)grow * 128 + l16;
#pragma unroll
                    for (int ni = 0; ni < 8; ++ni)
                        dst[ni * 16] = bf16_rne(acc[mi][ni][reg]);
                }
            }
    }

    if (MODE == 0 || MODE == 1) {
        __syncthreads();
        sstat[tid] = 0.0f;
        __syncthreads();
#pragma unroll
        for (int ni = 0; ni < 8; ++ni) {
            const int col = ni * 16 + l16;
            float s = 0.0f, q = 0.0f;
#pragma unroll
            for (int mi = 0; mi < 2; ++mi)
#pragma unroll
                for (int reg = 0; reg < 4; ++reg) {
                    const int grow = bm + w * 32 + mi * 16 + quad * 4 + reg;
                    if (grow < NTRIP) {
                        const float v = acc[mi][ni][reg];
                        s += v; q += v * v;
                    }
                }
            atomicAdd(&sstat[col], s);
            atomicAdd(&sstat[128 + col], q);
        }
        __syncthreads();
        if (tid < 128) {
            atomicAdd(&gsum[tid], sstat[tid]);
            atomicAdd(&gsq[tid], sstat[128 + tid]);
        }
    }

    if (MODE == 2) {
        float sf[4], hf[4], sc[4], hc[4];
#pragma unroll
        for (int ni = 0; ni < 4; ++ni) {
            const int col = ni * 16 + l16;
            sf[ni] = scales[256 + col];      hf[ni] = scales[384 + col];
            sc[ni] = scales[256 + 64 + col]; hc[ni] = scales[384 + 64 + col];
        }
#pragma unroll
        for (int mi = 0; mi < 2; ++mi)
#pragma unroll
            for (int reg = 0; reg < 4; ++reg) {
                const int grow = bm + w * 32 + mi * 16 + quad * 4 + reg;
                if (grow < NTRIP) {
                    const int e = idx_ji[grow];
                    float* dst = &agg[(size_t)e * 64 + l16];
#pragma unroll
                    for (int ni = 0; ni < 4; ++ni) {
                        const float fv = acc[mi][ni][reg] * sf[ni] + hf[ni];
                        const float cv = acc[mi][ni + 4][reg] * sc[ni] + hc[ni];
                        atomicAdd(dst + ni * 16, sigmoid_f(fv) * tanh_f(cv));
                    }
                }
            }
    }
}

// ---------------------------------------------------------------------------
// fast-path pass 2, two-phase: (1) coalesced c3h reads + gate -> LDS;
// (2) scatter in MODE2's proven pattern: per atomic instruction, lanes
// l16=0..15 cover 16 CONTIGUOUS columns of one edge (64B segments, 4 edges).
// 64 rows per block, grid = T/64.
// ---------------------------------------------------------------------------
__global__ __launch_bounds__(256) void k_apply3(
    const unsigned short* __restrict__ c3h, const float* __restrict__ scales,
    const int* __restrict__ idx_ji, float* __restrict__ agg)
{
    __shared__ float smsg[64][65];
    __shared__ float s_sf[64], s_hf[64], s_sc[64], s_hc[64];
    __shared__ int sedge[64];

    const int tid = threadIdx.x;
    if (tid < 64) {
        s_sf[tid] = scales[256 + tid]; s_hf[tid] = scales[384 + tid];
        s_sc[tid] = scales[320 + tid]; s_hc[tid] = scales[448 + tid];
    }
    __syncthreads();

    const int base = blockIdx.x * 64;
    const int r = tid >> 2;      // 0..63 row within block
    const int h = tid & 3;       // 16-col chunk
    const int row = base + r;
    if (h == 0) sedge[r] = idx_ji[row];

    const uint4* pf = reinterpret_cast<const uint4*>(&c3h[(size_t)row * 128 + h * 16]);
    const uint4 f0 = pf[0], f1 = pf[1];
    const uint4* pc = reinterpret_cast<const uint4*>(&c3h[(size_t)row * 128 + 64 + h * 16]);
    const uint4 c0 = pc[0], c1 = pc[1];
    const unsigned fw[8] = {f0.x, f0.y, f0.z, f0.w, f1.x, f1.y, f1.z, f1.w};
    const unsigned cw[8] = {c0.x, c0.y, c0.z, c0.w, c1.x, c1.y, c1.z, c1.w};
#pragma unroll
    for (int p = 0; p < 8; ++p) {
        const int col0 = h * 16 + 2 * p;
        const float fa = __uint_as_float(fw[p] << 16);
        const float fb = __uint_as_float(fw[p] & 0xFFFF0000u);
        const float ca = __uint_as_float(cw[p] << 16);
        const float cb = __uint_as_float(cw[p] & 0xFFFF0000u);
        smsg[r][col0] = sigmoid_f(fa * s_sf[col0] + s_hf[col0]) *
                        tanh_f(ca * s_sc[col0] + s_hc[col0]);
        smsg[r][col0 + 1] = sigmoid_f(fb * s_sf[col0 + 1] + s_hf[col0 + 1]) *
                            tanh_f(cb * s_sc[col0 + 1] + s_hc[col0 + 1]);
    }
    __syncthreads();

    // phase 2: wave w handles rows w*16 .. w*16+15
    const int w = tid >> 6;
    const int lane = tid & 63;
    const int quad = lane >> 4;
    const int l16 = lane & 15;
#pragma unroll
    for (int og = 0; og < 4; ++og) {
        const int rr = w * 16 + og * 4 + quad;
        float* dst = &agg[(size_t)sedge[rr] * 64];
#pragma unroll
        for (int ni = 0; ni < 4; ++ni)
            atomicAdd(dst + ni * 16 + l16, smsg[rr][ni * 16 + l16]);
    }
}

// ---------------------------------------------------------------------------
// c2 GEMM (K=64, VALU) — unchanged
// ---------------------------------------------------------------------------
template <int MODE>
__global__ __launch_bounds__(256) void k_gemm_c2(
    const float* __restrict__ node, const int* __restrict__ vi,
    const int* __restrict__ vj, const float* __restrict__ W2,
    float* __restrict__ gsum, float* __restrict__ gsq,
    const float* __restrict__ scales, float* __restrict__ uout,
    float* __restrict__ usum, float* __restrict__ usq)
{
    __shared__ float sA[32][132];
    __shared__ float sB[32][132];
    __shared__ float sstat[256];

    const int tid = threadIdx.x;
    const int tx = tid & 15, ty = tid >> 4;
    const int bm = blockIdx.x * 128;

    float acc[8][8];
#pragma unroll
    for (int i = 0; i < 8; ++i)
#pragma unroll
        for (int j = 0; j < 8; ++j) acc[i][j] = 0.0f;

    const int mstage = tid >> 1;
    const int kq = (tid & 1) * 16;
    int g = bm + mstage;
    if (g >= NEDGE) g = NEDGE - 1;
    const int r0 = vi[g], r1 = vj[g];

    for (int s = 0; s < 2; ++s) {
        const int kin = s * 32;
        const float4* pa = reinterpret_cast<const float4*>(node + (size_t)r0 * 64 + kin + kq);
        const float4* pc = reinterpret_cast<const float4*>(node + (size_t)r1 * 64 + kin + kq);
        float4 v0 = pa[0], v1 = pa[1], v2 = pa[2], v3 = pa[3];
        float4 u0 = pc[0], u1 = pc[1], u2 = pc[2], u3 = pc[3];
        const float4* pb = reinterpret_cast<const float4*>(W2 + (size_t)mstage * 64 + kin + kq);
        float4 w0 = pb[0], w1 = pb[1], w2 = pb[2], w3 = pb[3];

        __syncthreads();
        const float va[16] = {v0.x*u0.x, v0.y*u0.y, v0.z*u0.z, v0.w*u0.w,
                              v1.x*u1.x, v1.y*u1.y, v1.z*u1.z, v1.w*u1.w,
                              v2.x*u2.x, v2.y*u2.y, v2.z*u2.z, v2.w*u2.w,
                              v3.x*u3.x, v3.y*u3.y, v3.z*u3.z, v3.w*u3.w};
        const float vb[16] = {w0.x,w0.y,w0.z,w0.w, w1.x,w1.y,w1.z,w1.w,
                              w2.x,w2.y,w2.z,w2.w, w3.x,w3.y,w3.z,w3.w};
#pragma unroll
        for (int u = 0; u < 16; ++u) sA[kq + u][mstage] = va[u];
#pragma unroll
        for (int u = 0; u < 16; ++u) sB[kq + u][mstage] = vb[u];
        __syncthreads();

#pragma unroll 4
        for (int k = 0; k < 32; ++k) {
            const float4 a0 = *reinterpret_cast<const float4*>(&sA[k][ty * 4]);
            const float4 a1 = *reinterpret_cast<const float4*>(&sA[k][64 + ty * 4]);
            const float4 b0 = *reinterpret_cast<const float4*>(&sB[k][tx * 4]);
            const float4 b1 = *reinterpret_cast<const float4*>(&sB[k][64 + tx * 4]);
            const float av[8] = {a0.x,a0.y,a0.z,a0.w, a1.x,a1.y,a1.z,a1.w};
            const float bv[8] = {b0.x,b0.y,b0.z,b0.w, b1.x,b1.y,b1.z,b1.w};
#pragma unroll
            for (int i = 0; i < 8; ++i)
#pragma unroll
                for (int j = 0; j < 8; ++j)
                    acc[i][j] = fmaf(av[i], bv[j], acc[i][j]);
        }
    }

    int rowg[8];
#pragma unroll
    for (int i = 0; i < 8; ++i) {
        const int m = (i < 4) ? (ty * 4 + i) : (64 + ty * 4 + (i - 4));
        rowg[i] = bm + m;
    }

    if (MODE == 0) {
        __syncthreads();
        sstat[tid] = 0.0f;
        __syncthreads();
#pragma unroll
        for (int j = 0; j < 8; ++j) {
            const int n = (j < 4) ? (tx * 4 + j) : (64 + tx * 4 + (j - 4));
            float s = 0.0f, q = 0.0f;
#pragma unroll
            for (int i = 0; i < 8; ++i) {
                if (rowg[i] < NEDGE) { s += acc[i][j]; q += acc[i][j] * acc[i][j]; }
            }
            atomicAdd(&sstat[n], s);
            atomicAdd(&sstat[128 + n], q);
        }
        __syncthreads();
        if (tid < 128) {
            atomicAdd(&gsum[tid], sstat[tid]);
            atomicAdd(&gsq[tid], sstat[128 + tid]);
        }
    }

    if (MODE == 2) {
        float sf[4], hf[4], sc[4], hc[4];
#pragma unroll
        for (int j = 0; j < 4; ++j) {
            const int col = tx * 4 + j;
            sf[j] = scales[col];      hf[j] = scales[128 + col];
            sc[j] = scales[64 + col]; hc[j] = scales[128 + 64 + col];
        }
        __syncthreads();
        sstat[tid] = 0.0f;
        __syncthreads();
        float lsum[4] = {0, 0, 0, 0}, lsq[4] = {0, 0, 0, 0};
#pragma unroll
        for (int i = 0; i < 8; ++i) {
            if (rowg[i] < NEDGE) {
                float uv[4];
#pragma unroll
                for (int j = 0; j < 4; ++j) {
                    const float f = acc[i][j] * sf[j] + hf[j];
                    const float c = acc[i][j + 4] * sc[j] + hc[j];
                    uv[j] = sigmoid_f(f) * tanh_f(c);
                    lsum[j] += uv[j]; lsq[j] += uv[j] * uv[j];
                }
                *reinterpret_cast<float4*>(&uout[(size_t)rowg[i] * 64 + tx * 4]) =
                    make_float4(uv[0], uv[1], uv[2], uv[3]);
            }
        }
#pragma unroll
        for (int j = 0; j < 4; ++j) {
            atomicAdd(&sstat[tx * 4 + j], lsum[j]);
            atomicAdd(&sstat[128 + tx * 4 + j], lsq[j]);
        }
        __syncthreads();
        if (tid < 64) {
            atomicAdd(&usum[tid], sstat[tid]);
            atomicAdd(&usq[tid], sstat[128 + tid]);
        }
    }
}

// ---------------------------------------------------------------------------
__global__ void k_finalize1(const float* __restrict__ gstats,
                            const float* __restrict__ g_c2, const float* __restrict__ beta_c2,
                            const float* __restrict__ g_c3, const float* __restrict__ beta_c3,
                            float* __restrict__ scales)
{
    const int t = threadIdx.x;
    if (t < 128) {
        const float inv = 1.0f / (float)NEDGE;
        const float mean = gstats[t] * inv;
        const float var = gstats[128 + t] * inv - mean * mean;
        const float sc = g_c2[t] * rsqrtf(var + EPSBN);
        scales[t] = sc;
        scales[128 + t] = beta_c2[t] - mean * sc;
    } else {
        const int c = t - 128;
        const float inv = 1.0f / (float)NTRIP;
        const float mean = gstats[256 + c] * inv;
        const float var = gstats[384 + c] * inv - mean * mean;
        const float sc = g_c3[c] * rsqrtf(var + EPSBN);
        scales[256 + c] = sc;
        scales[384 + c] = beta_c3[c] - mean * sc;
    }
}

__global__ void k_finalize2(const float* __restrict__ gstats,
                            const float* __restrict__ g_c22, const float* __restrict__ beta_c22,
                            const float* __restrict__ g_c32, const float* __restrict__ beta_c32,
                            float* __restrict__ scales)
{
    const int t = threadIdx.x;
    const float inv = 1.0f / (float)NEDGE;
    if (t < 64) {
        const float mean = gstats[512 + t] * inv;
        const float var = gstats[576 + t] * inv - mean * mean;
        const float sc = g_c22[t] * rsqrtf(var + EPSBN);
        scales[512 + t] = sc;
        scales[576 + t] = beta_c22[t] - mean * sc;
    } else {
        const int c = t - 64;
        const float mean = gstats[640 + c] * inv;
        const float var = gstats[704 + c] * inv - mean * mean;
        const float sc = g_c32[c] * rsqrtf(var + EPSBN);
        scales[640 + c] = sc;
        scales[704 + c] = beta_c32[c] - mean * sc;
    }
}

// ---------------------------------------------------------------------------
__global__ __launch_bounds__(256) void k_stats_agg(
    const float* __restrict__ agg, float* __restrict__ gstats)
{
    const int tid = threadIdx.x;
    const int c4 = tid & 15;
    float ls[4] = {0, 0, 0, 0}, lq[4] = {0, 0, 0, 0};
    const long total = (long)NEDGE * 16;
    const long stride = (long)gridDim.x * blockDim.x;
    for (long idx = (long)blockIdx.x * blockDim.x + tid; idx < total; idx += stride) {
        const int row = (int)(idx >> 4);
        const float4 a = *reinterpret_cast<const float4*>(&agg[(size_t)row * 64 + c4 * 4]);
        ls[0] += a.x; lq[0] += a.x * a.x;
        ls[1] += a.y; lq[1] += a.y * a.y;
        ls[2] += a.z; lq[2] += a.z * a.z;
        ls[3] += a.w; lq[3] += a.w * a.w;
    }
    __shared__ float red[2][16][68];
    const int gr = tid >> 4;
#pragma unroll
    for (int cc = 0; cc < 4; ++cc) {
        red[0][gr][c4 * 4 + cc] = ls[cc];
        red[1][gr][c4 * 4 + cc] = lq[cc];
    }
    __syncthreads();
    if (tid < 64) {
        float s = 0.0f, q = 0.0f;
        for (int g2 = 0; g2 < 16; ++g2) { s += red[0][g2][tid]; q += red[1][g2][tid]; }
        atomicAdd(&gstats[640 + tid], s);
        atomicAdd(&gstats[704 + tid], q);
    }
}

// ---------------------------------------------------------------------------
__global__ __launch_bounds__(256) void k_final(
    const float* __restrict__ edge, const float* __restrict__ agg,
    const float* __restrict__ scales, float* __restrict__ out)
{
    const int tid = threadIdx.x;
    const int c4 = tid & 15;
    float su[4], hu[4], sa[4], ha[4];
#pragma unroll
    for (int cc = 0; cc < 4; ++cc) {
        const int col = c4 * 4 + cc;
        su[cc] = scales[512 + col]; hu[cc] = scales[576 + col];
        sa[cc] = scales[640 + col]; ha[cc] = scales[704 + col];
    }
    const long total = (long)NEDGE * 16;
    const long stride = (long)gridDim.x * blockDim.x;
    for (long idx = (long)blockIdx.x * blockDim.x + tid; idx < total; idx += stride) {
        const int row = (int)(idx >> 4);
        const size_t base = (size_t)row * 64 + c4 * 4;
        const float4 e = *reinterpret_cast<const float4*>(&edge[base]);
        const float4 u = *reinterpret_cast<const float4*>(&out[base]);
        const float4 a = *reinterpret_cast<const float4*>(&agg[base]);
        float4 o;
        o.x = tanh_f(e.x + u.x * su[0] + hu[0] + a.x * sa[0] + ha[0]);
        o.y = tanh_f(e.y + u.y * su[1] + hu[1] + a.y * sa[1] + ha[1]);
        o.z = tanh_f(e.z + u.z * su[2] + hu[2] + a.z * sa[2] + ha[2]);
        o.w = tanh_f(e.w + u.w * su[3] + hu[3] + a.w * sa[3] + ha[3]);
        *reinterpret_cast<float4*>(&out[base]) = o;
    }
}

// ---------------------------------------------------------------------------
extern "C" void kernel_launch(void* const* d_in, const int* in_sizes, int n_in,
                              void* d_out, int out_size, void* d_ws, size_t ws_size,
                              hipStream_t stream)
{
    (void)in_sizes; (void)n_in; (void)out_size;
    const float* node   = (const float*)d_in[0];
    const float* edge   = (const float*)d_in[1];
    const int*   vi     = (const int*)d_in[2];
    const int*   vj     = (const int*)d_in[3];
    const int*   idx_i  = (const int*)d_in[4];
    const int*   idx_j  = (const int*)d_in[5];
    const int*   idx_k  = (const int*)d_in[6];
    const int*   idx_ji = (const int*)d_in[7];
    const int*   idx_kj = (const int*)d_in[8];
    const float* W2     = (const float*)d_in[9];
    // d_in[10] = b2: cancels inside BN (mean subtraction)
    const float* W3     = (const float*)d_in[11];
    // d_in[12] = b3: cancels inside BN
    const float* g_c2    = (const float*)d_in[13];
    const float* beta_c2 = (const float*)d_in[14];
    const float* g_c3    = (const float*)d_in[15];
    const float* beta_c3 = (const float*)d_in[16];
    const float* g_c22    = (const float*)d_in[17];
    const float* beta_c22 = (const float*)d_in[18];
    const float* g_c32    = (const float*)d_in[19];
    const float* beta_c32 = (const float*)d_in[20];
    float* out = (float*)d_out;

    unsigned* wsu   = (unsigned*)d_ws;
    float* gstats   = (float*)wsu;                    // u32 [0:768)
    float* scales   = (float*)(wsu + 768);            // [768:1536)
    unsigned* w3f_hi = wsu + 1536;                    // [1536:22016)
    unsigned* w3f_lo = wsu + 22016;                   // [22016:42496)
    float* agg      = (float*)(wsu + 42496);          // E*64 floats
    unsigned short* c3h = (unsigned short*)(wsu + 42496 + (size_t)NEDGE * 64);

    const size_t need_fast =
        (42496 + (size_t)NEDGE * 64 + (size_t)NTRIP * 64) * 4;  // ~205 MB
    const bool fast = (ws_size >= need_fast);

    hipMemsetAsync(gstats, 0, 768 * sizeof(float), stream);
    hipMemsetAsync(agg, 0, (size_t)NEDGE * 64 * sizeof(float), stream);

    const int grid_c2 = (NEDGE + 127) / 128;
    const int grid_c3 = (NTRIP + 127) / 128;

    k_pack_w3<<<80, 256, 0, stream>>>(W3, w3f_hi, w3f_lo);

    // pass 1: column stats (fast: 3-term + bf16 store of c3; slow: 1-term)
    k_gemm_c2<0><<<grid_c2, 256, 0, stream>>>(
        node, vi, vj, W2, gstats + 0, gstats + 128, nullptr, nullptr, nullptr, nullptr);
    if (fast) {
        k_gemm_c3_mfma<1><<<grid_c3, 256, 0, stream>>>(
            node, edge, idx_i, idx_j, idx_k, idx_ji, idx_kj, w3f_hi, w3f_lo,
            gstats + 256, gstats + 384, nullptr, nullptr, c3h);
    } else {
        k_gemm_c3_mfma<0><<<grid_c3, 256, 0, stream>>>(
            node, edge, idx_i, idx_j, idx_k, idx_ji, idx_kj, w3f_hi, w3f_lo,
            gstats + 256, gstats + 384, nullptr, nullptr, nullptr);
    }
    k_finalize1<<<1, 256, 0, stream>>>(gstats, g_c2, beta_c2, g_c3, beta_c3, scales);

    // pass 2: apply BN + gates; u -> d_out (scratch), msg -> agg (atomics)
    k_gemm_c2<2><<<grid_c2, 256, 0, stream>>>(
        node, vi, vj, W2, nullptr, nullptr, scales, out, gstats + 512, gstats + 576);
    if (fast) {
        k_apply3<<<NTRIP / 64, 256, 0, stream>>>(c3h, scales, idx_ji, agg);
    } else {
        k_gemm_c3_mfma<2><<<grid_c3, 256, 0, stream>>>(
            node, edge, idx_i, idx_j, idx_k, idx_ji, idx_kj, w3f_hi, w3f_lo,
            nullptr, nullptr, scales, agg, nullptr);
    }

    k_stats_agg<<<3072, 256, 0, stream>>>(agg, gstats);
    k_finalize2<<<1, 128, 0, stream>>>(gstats, g_c22, beta_c22, g_c32, beta_c32, scales);
    k_final<<<3072, 256, 0, stream>>>(edge, agg, scales, out);
}